// Round 7
// baseline (673.149 us; speedup 1.0000x reference)
//
#include <hip/hip_runtime.h>

#define NS 128
#define EPSF 1e-10f
#define FAR_DIST 1e10f

typedef float f4 __attribute__((ext_vector_type(4)));

__global__ __launch_bounds__(256) void volrend_kernel(
    const float* __restrict__ rays_d,
    const float* __restrict__ rgb,
    const float* __restrict__ sigma,
    float* __restrict__ rgb_map,
    float* __restrict__ depth_map,
    float* __restrict__ weights,
    float* __restrict__ z_out,
    int N)
{
    // 2 rays per wave (32-lane segments), 4 samples per lane
    const int wid  = threadIdx.x >> 6;
    const int lane = threadIdx.x & 63;
    const int half = lane >> 5;        // which ray within the wave
    const int sl   = lane & 31;        // sub-lane within the ray's segment
    const int ray  = (blockIdx.x * 4 + wid) * 2 + half;
    if (ray >= N) return;

    const float dx = rays_d[ray * 3 + 0];
    const float dy = rays_d[ray * 3 + 1];
    const float dz = rays_d[ray * 3 + 2];
    const float nrm = sqrtf(dx * dx + dy * dy + dz * dz);

    // samples s .. s+3
    const int s = sl * 4;
    const float c = 1.0f / 127.0f;     // matches jnp.linspace's i*step
    float z[4], d[4];
    #pragma unroll
    for (int j = 0; j < 4; ++j) {
        z[j] = (float)(s + j) * c;
        const float zn = (float)(s + j + 1) * c;
        d[j] = ((s + j == 127) ? FAR_DIST : (zn - z[j])) * nrm;
    }

    const size_t base = (size_t)ray * NS + s;
    const f4 sg = __builtin_nontemporal_load(
        reinterpret_cast<const f4*>(sigma + base));

    float a[4], f[4];
    #pragma unroll
    for (int j = 0; j < 4; ++j) {
        a[j] = 1.0f - __expf(-sg[j] * d[j]);
        f[j] = 1.0f - a[j] + EPSF;
    }

    // inclusive prefix product of per-lane factor product, width-32 segments
    float p = (f[0] * f[1]) * (f[2] * f[3]);
    #pragma unroll
    for (int off = 1; off < 32; off <<= 1) {
        const float t = __shfl_up(p, off, 32);
        if (sl >= off) p *= t;
    }
    const float ex = __shfl_up(p, 1, 32);
    const float t0 = (sl == 0) ? 1.0f : ex;   // T[s] = prod f[0..s-1]
    const float t1 = t0 * f[0];
    const float t2 = t1 * f[1];
    const float t3 = t2 * f[2];

    const float w0 = a[0] * t0;
    const float w1 = a[1] * t1;
    const float w2 = a[2] * t2;
    const float w3 = a[3] * t3;

    // nontemporal 16B stores: bypass L2 write-allocate (streams never re-read)
    const f4 wv = {w0, w1, w2, w3};
    const f4 zv = {z[0], z[1], z[2], z[3]};
    __builtin_nontemporal_store(wv, reinterpret_cast<f4*>(weights + base));
    __builtin_nontemporal_store(zv, reinterpret_cast<f4*>(z_out + base));

    // rgb: 12 contiguous floats per lane (48B, 16B-aligned) as three f4 loads
    const float* rrow = rgb + (size_t)ray * NS * 3 + 12 * sl;
    const f4 u0 = __builtin_nontemporal_load(reinterpret_cast<const f4*>(rrow + 0));
    const f4 u1 = __builtin_nontemporal_load(reinterpret_cast<const f4*>(rrow + 4));
    const f4 u2 = __builtin_nontemporal_load(reinterpret_cast<const f4*>(rrow + 8));
    // element e = 12*sl + k : sample s + k/3, channel k%3
    float accr = w0 * u0[0] + w1 * u0[3] + w2 * u1[2] + w3 * u2[1];
    float accg = w0 * u0[1] + w1 * u1[0] + w2 * u1[3] + w3 * u2[2];
    float accb = w0 * u0[2] + w1 * u1[1] + w2 * u2[0] + w3 * u2[3];
    float accd = w0 * z[0] + w1 * z[1] + w2 * z[2] + w3 * z[3];

    #pragma unroll
    for (int off = 16; off >= 1; off >>= 1) {
        accr += __shfl_down(accr, off, 32);
        accg += __shfl_down(accg, off, 32);
        accb += __shfl_down(accb, off, 32);
        accd += __shfl_down(accd, off, 32);
    }
    if (sl == 0) {
        rgb_map[(size_t)ray * 3 + 0] = accr;
        rgb_map[(size_t)ray * 3 + 1] = accg;
        rgb_map[(size_t)ray * 3 + 2] = accb;
        depth_map[ray] = accd;
    }
}

extern "C" void kernel_launch(void* const* d_in, const int* in_sizes, int n_in,
                              void* d_out, int out_size, void* d_ws, size_t ws_size,
                              hipStream_t stream) {
    // setup_inputs order: rays_o, rays_d, rgb, sigma
    const float* rays_d = (const float*)d_in[1];
    const float* rgb    = (const float*)d_in[2];
    const float* sigma  = (const float*)d_in[3];
    const int N = in_sizes[0] / 3;

    float* out       = (float*)d_out;
    float* rgb_map   = out;                                   // [N,3]
    float* depth_map = out + (size_t)N * 3;                   // [N]
    float* weights   = out + (size_t)N * 4;                   // [N,128]
    float* z_vals    = out + (size_t)N * 4 + (size_t)N * NS;  // [N,128]

    const int blocks = (N + 7) / 8;  // 8 rays per 256-thread block (2 per wave)
    volrend_kernel<<<blocks, 256, 0, stream>>>(
        rays_d, rgb, sigma, rgb_map, depth_map, weights, z_vals, N);
}